// Round 1
// baseline (139.697 us; speedup 1.0000x reference)
//
#include <hip/hip_runtime.h>
#include <hip/hip_bf16.h>

#define HW   8192
#define W0   128
#define H0   64
#define CDIM 256

// ---------- bf16 helpers (OCP bf16 as raw ushort) ----------
__device__ __forceinline__ float bflo(unsigned int d) {
    union { unsigned int i; float f; } v; v.i = d << 16; return v.f;
}
__device__ __forceinline__ float bfhi(unsigned int d) {
    union { unsigned int i; float f; } v; v.i = d & 0xffff0000u; return v.f;
}
__device__ __forceinline__ float bf2f(unsigned short u) {
    union { unsigned int i; float f; } v; v.i = ((unsigned int)u) << 16; return v.f;
}
__device__ __forceinline__ unsigned short f2bf(float f) {
    unsigned int x = __float_as_uint(f);
    unsigned int r = (x + 0x7fffu + ((x >> 16) & 1u)) >> 16;  // RNE
    return (unsigned short)r;
}

// ---------- K1: transpose fmap1 [256][8192] -> f1T [8192][256], scaled 1/16 ----------
__global__ __launch_bounds__(256) void k_transpose_f1(const float* __restrict__ in,
                                                      float* __restrict__ outT) {
    __shared__ float lds[32][257];
    const int m0 = blockIdx.x * 32;
    const int tc = threadIdx.x & 31;   // local m
    const int tr = threadIdx.x >> 5;   // 0..7
    #pragma unroll 4
    for (int r = 0; r < 32; ++r) {
        const int c = r * 8 + tr;
        lds[tc][c] = in[(size_t)c * HW + m0 + tc] * 0.0625f;
    }
    __syncthreads();
    const int c = threadIdx.x;
    #pragma unroll 4
    for (int ml = 0; ml < 32; ++ml) {
        outT[(size_t)(m0 + ml) * CDIM + c] = lds[ml][c];
    }
}

// ---------- K2: transpose fmap2 [256][8192] -> pyramid level0 HWC bf16 ----------
__global__ __launch_bounds__(256) void k_transpose_f2(const float* __restrict__ in,
                                                      unsigned short* __restrict__ outT) {
    __shared__ float lds[32][257];
    const int m0 = blockIdx.x * 32;
    const int tc = threadIdx.x & 31;
    const int tr = threadIdx.x >> 5;
    #pragma unroll 4
    for (int r = 0; r < 32; ++r) {
        const int c = r * 8 + tr;
        lds[tc][c] = in[(size_t)c * HW + m0 + tc];
    }
    __syncthreads();
    const int c = threadIdx.x;
    #pragma unroll 4
    for (int ml = 0; ml < 32; ++ml) {
        outT[(size_t)(m0 + ml) * CDIM + c] = f2bf(lds[ml][c]);
    }
}

// ---------- K3: 2x2 avg pool, HWC bf16 -> HWC bf16 ----------
__global__ __launch_bounds__(256) void k_pool(const unsigned short* __restrict__ in,
                                              unsigned short* __restrict__ out,
                                              int Wout, int Win) {
    const int c = threadIdx.x;
    const int b = blockIdx.x;           // Y*Wout + X
    const int X = b % Wout;
    const int Y = b / Wout;
    const size_t base = ((size_t)(2 * Y) * Win + 2 * X) * CDIM + c;
    const size_t rows = (size_t)Win * CDIM;
    float s = bf2f(in[base]) + bf2f(in[base + CDIM]) +
              bf2f(in[base + rows]) + bf2f(in[base + rows + CDIM]);
    out[(size_t)b * CDIM + c] = f2bf(s * 0.25f);
}

// ---------- K4: fused correlation sampling ----------
// 1 block per pixel, 4 waves; wave w handles pyramid level w.
// Each 32-lane half computes one 256-ch dot product per step (8 ch/lane).
__global__ __launch_bounds__(256) void k_sample(const float* __restrict__ f1T,
                                                const unsigned short* __restrict__ pyr,
                                                const float* __restrict__ coords,
                                                float* __restrict__ out) {
    const int m    = blockIdx.x;
    const int tid  = threadIdx.x;
    const int w    = tid >> 6;      // level
    const int lane = tid & 63;
    const int half = lane >> 5;
    const int sub  = lane & 31;
    const int c0   = sub * 8;

    __shared__ float sG[4][100];
    __shared__ float sF[4][2];      // fx, fy per level

    // f1 fragment: 8 channels per lane (pre-scaled by 1/16)
    const float4* f1p = reinterpret_cast<const float4*>(f1T + (size_t)m * CDIM + c0);
    const float4 fA = f1p[0];
    const float4 fB = f1p[1];

    const float cx = coords[m];
    const float cy = coords[HW + m];
    const float scale = 1.0f / (float)(1 << w);
    const float xs = cx * scale;
    const float ys = cy * scale;
    const float X0f = floorf(xs);
    const float Y0f = floorf(ys);
    const int X0 = (int)X0f;
    const int Y0 = (int)Y0f;
    if (lane == 0) { sF[w][0] = xs - X0f; sF[w][1] = ys - Y0f; }

    const int Wl = W0 >> w;
    const int Hl = H0 >> w;
    const size_t lvl_off = (w == 0) ? 0u
                         : (w == 1) ? 2097152u
                         : (w == 2) ? 2621440u
                         :            2752512u;
    const unsigned short* lvl = pyr + lvl_off;

    for (int j = 0; j < 10; ++j) {
        const int gy = Y0 - 4 + j;
        const bool yok = ((unsigned)gy < (unsigned)Hl);
        const long rowb = (long)gy * Wl;
        #pragma unroll
        for (int t = 0; t < 5; ++t) {
            const int i  = 2 * t + half;
            const int gx = X0 - 4 + i;
            float s = 0.0f;
            if (yok && ((unsigned)gx < (unsigned)Wl)) {
                const uint4 u = *reinterpret_cast<const uint4*>(
                    lvl + ((size_t)(rowb + gx) * CDIM + c0));
                s = fA.x * bflo(u.x) + fA.y * bfhi(u.x)
                  + fA.z * bflo(u.y) + fA.w * bfhi(u.y)
                  + fB.x * bflo(u.z) + fB.y * bfhi(u.z)
                  + fB.z * bflo(u.w) + fB.w * bfhi(u.w);
            }
            // reduce across the 32-lane half (both halves independently)
            s += __shfl_xor(s, 1);
            s += __shfl_xor(s, 2);
            s += __shfl_xor(s, 4);
            s += __shfl_xor(s, 8);
            s += __shfl_xor(s, 16);
            if (sub == 0) sG[w][j * 10 + i] = s;
        }
    }
    __syncthreads();

    // combine 10x10 grid into 81 outputs per level with shared bilinear weights
    for (int o = tid; o < 324; o += 256) {
        const int lev = o / 81;
        const int k   = o - lev * 81;
        const int a   = k / 9;          // x-offset index (torch meshgrid quirk)
        const int b   = k - a * 9;      // y-offset index
        const float fx = sF[lev][0], fy = sF[lev][1];
        const float wx0 = 1.0f - fx, wx1 = fx;
        const float wy0 = 1.0f - fy, wy1 = fy;
        const float* G = sG[lev];
        const float v = wy0 * (wx0 * G[b * 10 + a]       + wx1 * G[b * 10 + a + 1])
                      + wy1 * (wx0 * G[(b + 1) * 10 + a] + wx1 * G[(b + 1) * 10 + a + 1]);
        out[(size_t)o * HW + m] = v;
    }
}

extern "C" void kernel_launch(void* const* d_in, const int* in_sizes, int n_in,
                              void* d_out, int out_size, void* d_ws, size_t ws_size,
                              hipStream_t stream) {
    const float* fmap1  = (const float*)d_in[0];
    const float* fmap2  = (const float*)d_in[1];
    const float* coords = (const float*)d_in[2];
    float* out = (float*)d_out;

    char* ws = (char*)d_ws;
    float* f1T = (float*)ws;                                   // 8192*256 f32 = 8 MiB
    unsigned short* pyr = (unsigned short*)(ws + 8388608);     // 2,785,280 bf16 = 5.57 MB
    unsigned short* p0 = pyr;                 // 64x128x256
    unsigned short* p1 = pyr + 2097152;       // 32x64x256
    unsigned short* p2 = pyr + 2621440;       // 16x32x256
    unsigned short* p3 = pyr + 2752512;       //  8x16x256

    k_transpose_f1<<<HW / 32, 256, 0, stream>>>(fmap1, f1T);
    k_transpose_f2<<<HW / 32, 256, 0, stream>>>(fmap2, p0);
    k_pool<<<32 * 64, 256, 0, stream>>>(p0, p1, 64, 128);
    k_pool<<<16 * 32, 256, 0, stream>>>(p1, p2, 32, 64);
    k_pool<<<8 * 16, 256, 0, stream>>>(p2, p3, 16, 32);
    k_sample<<<HW, 256, 0, stream>>>(f1T, pyr, coords, out);
}

// Round 5
// 122.986 us; speedup vs baseline: 1.1359x; 1.1359x over previous
//
#include <hip/hip_runtime.h>
#include <hip/hip_bf16.h>

#define HW   8192
#define W0   128
#define H0   64
#define CDIM 256

typedef _Float16 half2v __attribute__((ext_vector_type(2)));

__device__ __forceinline__ float dot2u(unsigned int a, unsigned int b, float acc) {
    union { unsigned int u; half2v h; } ua, ub;
    ua.u = a; ub.u = b;
#if __has_builtin(__builtin_amdgcn_fdot2)
    return __builtin_amdgcn_fdot2(ua.h, ub.h, acc, false);
#else
    return acc + (float)ua.h.x * (float)ub.h.x + (float)ua.h.y * (float)ub.h.y;
#endif
}

// ---------- K1: transpose fmap1 [256][8192] -> f1T [8192][256] f16, scaled 1/16 ----------
__global__ __launch_bounds__(256) void k_transpose_f1(const float* __restrict__ in,
                                                      _Float16* __restrict__ outT) {
    __shared__ float lds[32][257];
    const int m0 = blockIdx.x * 32;
    const int tc = threadIdx.x & 31;
    const int tr = threadIdx.x >> 5;
    #pragma unroll 4
    for (int r = 0; r < 32; ++r) {
        const int c = r * 8 + tr;
        lds[tc][c] = in[(size_t)c * HW + m0 + tc] * 0.0625f;
    }
    __syncthreads();
    const int c = threadIdx.x;
    #pragma unroll 4
    for (int ml = 0; ml < 32; ++ml) {
        outT[(size_t)(m0 + ml) * CDIM + c] = (_Float16)lds[ml][c];
    }
}

// ---------- K2: transpose fmap2 [256][8192] -> pyramid level0 HWC f16 ----------
__global__ __launch_bounds__(256) void k_transpose_f2(const float* __restrict__ in,
                                                      _Float16* __restrict__ outT) {
    __shared__ float lds[32][257];
    const int m0 = blockIdx.x * 32;
    const int tc = threadIdx.x & 31;
    const int tr = threadIdx.x >> 5;
    #pragma unroll 4
    for (int r = 0; r < 32; ++r) {
        const int c = r * 8 + tr;
        lds[tc][c] = in[(size_t)c * HW + m0 + tc];
    }
    __syncthreads();
    const int c = threadIdx.x;
    #pragma unroll 4
    for (int ml = 0; ml < 32; ++ml) {
        outT[(size_t)(m0 + ml) * CDIM + c] = (_Float16)lds[ml][c];
    }
}

// ---------- K3: 2x2 avg pool, HWC f16 -> HWC f16 ----------
__global__ __launch_bounds__(256) void k_pool(const _Float16* __restrict__ in,
                                              _Float16* __restrict__ out,
                                              int Wout, int Win) {
    const int c = threadIdx.x;
    const int b = blockIdx.x;           // Y*Wout + X
    const int X = b % Wout;
    const int Y = b / Wout;
    const size_t base = ((size_t)(2 * Y) * Win + 2 * X) * CDIM + c;
    const size_t rows = (size_t)Win * CDIM;
    float s = (float)in[base] + (float)in[base + CDIM] +
              (float)in[base + rows] + (float)in[base + rows + CDIM];
    out[(size_t)b * CDIM + c] = (_Float16)(s * 0.25f);
}

// ---------- K4: fused correlation sampling ----------
// 1 block per 16 pixels, 4 waves; wave w = pyramid level w.
// 8 lanes per grid point: each lane covers 32 channels (4 uint4 of packed f16),
// 16 v_dot2_f32_f16 per lane, then a 3-step shuffle reduce.
__global__ __launch_bounds__(256) void k_sample(const _Float16* __restrict__ f1T,
                                                const _Float16* __restrict__ pyr,
                                                const float* __restrict__ coords,
                                                float* __restrict__ out) {
    const int tid  = threadIdx.x;
    const int w    = tid >> 6;      // level
    const int lane = tid & 63;
    const int grp  = lane >> 3;     // 8 point-groups per wave
    const int sub  = lane & 7;      // 8 lanes per point
    const int m0   = blockIdx.x * 16;

    __shared__ float sG[16][4][105];  // 105 pad: px-stride 420 -> bank offset 4/px
    __shared__ float sF[16][4][2];    // fx, fy

    const int Wl = W0 >> w;
    const int Hl = H0 >> w;
    const size_t lvl_off = (w == 0) ? 0u
                         : (w == 1) ? 2097152u
                         : (w == 2) ? 2621440u
                         :            2752512u;
    const _Float16* lvl = pyr + lvl_off;
    const float scale = 1.0f / (float)(1 << w);

    for (int px = 0; px < 16; ++px) {
        const int m = m0 + px;
        // f1 fragment: 32 channels (64 B) per lane, reused across 100 points
        const uint4* f1p = reinterpret_cast<const uint4*>(f1T + (size_t)m * CDIM + sub * 32);
        const uint4 F0 = f1p[0], F1 = f1p[1], F2 = f1p[2], F3 = f1p[3];

        const float xs = coords[m] * scale;
        const float ys = coords[HW + m] * scale;
        const float X0f = floorf(xs), Y0f = floorf(ys);
        const int X0 = (int)X0f, Y0 = (int)Y0f;
        if (lane == 0) { sF[px][w][0] = xs - X0f; sF[px][w][1] = ys - Y0f; }

        for (int it = 0; it < 13; ++it) {
            const int p = it * 8 + grp;           // grid point 0..103 (mask >=100)
            const int j = (p * 205) >> 11;        // p / 10
            const int i = p - j * 10;
            const int gy = Y0 - 4 + j;
            const int gx = X0 - 4 + i;
            float s = 0.0f;
            if (p < 100 && ((unsigned)gy < (unsigned)Hl) && ((unsigned)gx < (unsigned)Wl)) {
                const uint4* q = reinterpret_cast<const uint4*>(
                    lvl + ((size_t)(gy * Wl + gx) * CDIM) + sub * 32);
                const uint4 A = q[0], B = q[1], C = q[2], D = q[3];
                float s0 = 0.f, s1 = 0.f, s2 = 0.f, s3 = 0.f;
                s0 = dot2u(A.x, F0.x, s0); s0 = dot2u(A.y, F0.y, s0);
                s0 = dot2u(A.z, F0.z, s0); s0 = dot2u(A.w, F0.w, s0);
                s1 = dot2u(B.x, F1.x, s1); s1 = dot2u(B.y, F1.y, s1);
                s1 = dot2u(B.z, F1.z, s1); s1 = dot2u(B.w, F1.w, s1);
                s2 = dot2u(C.x, F2.x, s2); s2 = dot2u(C.y, F2.y, s2);
                s2 = dot2u(C.z, F2.z, s2); s2 = dot2u(C.w, F2.w, s2);
                s3 = dot2u(D.x, F3.x, s3); s3 = dot2u(D.y, F3.y, s3);
                s3 = dot2u(D.z, F3.z, s3); s3 = dot2u(D.w, F3.w, s3);
                s = (s0 + s1) + (s2 + s3);
            }
            // reduce across the 8 lanes of this point-group
            s += __shfl_xor(s, 1);
            s += __shfl_xor(s, 2);
            s += __shfl_xor(s, 4);
            if (sub == 0 && p < 100) sG[px][w][p] = s;
        }
    }
    __syncthreads();

    // combine: thread t -> pixel (t&15), channels (t>>4), (t>>4)+16, ...
    const int cpx   = tid & 15;
    const int obase = tid >> 4;
    for (int o = obase; o < 324; o += 16) {
        const int lev = (o * 811) >> 16;          // o / 81
        const int k   = o - lev * 81;
        const int a   = (k * 57) >> 9;            // k / 9  (x-offset index)
        const int b   = k - a * 9;                // k % 9  (y-offset index)
        const float fx = sF[cpx][lev][0], fy = sF[cpx][lev][1];
        const float wx0 = 1.0f - fx, wy0 = 1.0f - fy;
        const float* G = sG[cpx][lev];
        const float v = wy0 * (wx0 * G[b * 10 + a]       + fx * G[b * 10 + a + 1])
                      + fy  * (wx0 * G[(b + 1) * 10 + a] + fx * G[(b + 1) * 10 + a + 1]);
        out[(size_t)o * HW + m0 + cpx] = v;
    }
}

extern "C" void kernel_launch(void* const* d_in, const int* in_sizes, int n_in,
                              void* d_out, int out_size, void* d_ws, size_t ws_size,
                              hipStream_t stream) {
    const float* fmap1  = (const float*)d_in[0];
    const float* fmap2  = (const float*)d_in[1];
    const float* coords = (const float*)d_in[2];
    float* out = (float*)d_out;

    char* ws = (char*)d_ws;
    _Float16* f1T = (_Float16*)ws;                          // 8192*256 f16 = 4 MiB
    _Float16* pyr = (_Float16*)(ws + 4194304);              // 2,785,280 f16 = 5.57 MB
    _Float16* p0 = pyr;                 // 64x128x256
    _Float16* p1 = pyr + 2097152;       // 32x64x256
    _Float16* p2 = pyr + 2621440;       // 16x32x256
    _Float16* p3 = pyr + 2752512;       //  8x16x256

    k_transpose_f1<<<HW / 32, 256, 0, stream>>>(fmap1, f1T);
    k_transpose_f2<<<HW / 32, 256, 0, stream>>>(fmap2, p0);
    k_pool<<<32 * 64, 256, 0, stream>>>(p0, p1, 64, 128);
    k_pool<<<16 * 32, 256, 0, stream>>>(p1, p2, 32, 64);
    k_pool<<<8 * 16, 256, 0, stream>>>(p2, p3, 16, 32);
    k_sample<<<HW / 16, 256, 0, stream>>>(f1T, pyr, coords, out);
}

// Round 6
// 120.633 us; speedup vs baseline: 1.1580x; 1.0195x over previous
//
#include <hip/hip_runtime.h>
#include <hip/hip_bf16.h>

#define HW   8192
#define W0   128
#define H0   64
#define CDIM 256

typedef _Float16 half2v __attribute__((ext_vector_type(2)));

__device__ __forceinline__ float dot2u(unsigned int a, unsigned int b, float acc) {
    union { unsigned int u; half2v h; } ua, ub;
    ua.u = a; ub.u = b;
#if __has_builtin(__builtin_amdgcn_fdot2)
    return __builtin_amdgcn_fdot2(ua.h, ub.h, acc, false);
#else
    return acc + (float)ua.h.x * (float)ub.h.x + (float)ua.h.y * (float)ub.h.y;
#endif
}

// ---------- K1: transpose fmap1 [256][8192] -> f1T [8192][256] f16, scaled 1/16 ----------
__global__ __launch_bounds__(256) void k_transpose_f1(const float* __restrict__ in,
                                                      _Float16* __restrict__ outT) {
    __shared__ float lds[32][257];
    const int m0 = blockIdx.x * 32;
    const int tc = threadIdx.x & 31;
    const int tr = threadIdx.x >> 5;
    #pragma unroll 4
    for (int r = 0; r < 32; ++r) {
        const int c = r * 8 + tr;
        lds[tc][c] = in[(size_t)c * HW + m0 + tc] * 0.0625f;
    }
    __syncthreads();
    const int c = threadIdx.x;
    #pragma unroll 4
    for (int ml = 0; ml < 32; ++ml) {
        outT[(size_t)(m0 + ml) * CDIM + c] = (_Float16)lds[ml][c];
    }
}

// ---------- K2: transpose fmap2 [256][8192] -> pyramid level0 HWC f16 ----------
__global__ __launch_bounds__(256) void k_transpose_f2(const float* __restrict__ in,
                                                      _Float16* __restrict__ outT) {
    __shared__ float lds[32][257];
    const int m0 = blockIdx.x * 32;
    const int tc = threadIdx.x & 31;
    const int tr = threadIdx.x >> 5;
    #pragma unroll 4
    for (int r = 0; r < 32; ++r) {
        const int c = r * 8 + tr;
        lds[tc][c] = in[(size_t)c * HW + m0 + tc];
    }
    __syncthreads();
    const int c = threadIdx.x;
    #pragma unroll 4
    for (int ml = 0; ml < 32; ++ml) {
        outT[(size_t)(m0 + ml) * CDIM + c] = (_Float16)lds[ml][c];
    }
}

// ---------- K3: 2x2 avg pool, HWC f16 -> HWC f16 ----------
__global__ __launch_bounds__(256) void k_pool(const _Float16* __restrict__ in,
                                              _Float16* __restrict__ out,
                                              int Wout, int Win) {
    const int c = threadIdx.x;
    const int b = blockIdx.x;           // Y*Wout + X
    const int X = b % Wout;
    const int Y = b / Wout;
    const size_t base = ((size_t)(2 * Y) * Win + 2 * X) * CDIM + c;
    const size_t rows = (size_t)Win * CDIM;
    float s = (float)in[base] + (float)in[base + CDIM] +
              (float)in[base + rows] + (float)in[base + rows + CDIM];
    out[(size_t)b * CDIM + c] = (_Float16)(s * 0.25f);
}

// ---------- K4: fused correlation sampling ----------
// 512 blocks x 1024 threads (16 waves). Wave wv = pixel m0+wv, all 4 levels.
// 8 lanes per grid point, 32 channels/lane (4 uint4 of packed f16), 16 dot2,
// 3-step shuffle reduce. f1 fragment loaded ONCE per pixel, reused 4 levels.
// XCD-chunked block swizzle: each XCD gets 64 consecutive blocks = 8 image rows.
__global__ __launch_bounds__(1024, 8) void k_sample(const _Float16* __restrict__ f1T,
                                                    const _Float16* __restrict__ pyr,
                                                    const float* __restrict__ coords,
                                                    float* __restrict__ out) {
    const int tid  = threadIdx.x;
    const int wv   = tid >> 6;      // wave = pixel within block (0..15)
    const int lane = tid & 63;
    const int grp  = lane >> 3;     // 8 point-groups per wave
    const int sub  = lane & 7;      // 8 lanes per point

    // bijective XCD-chunk swizzle: 512 blocks, 8 XCDs, chunk 64
    const int b  = blockIdx.x;
    const int sb = (b & 7) * 64 + (b >> 3);
    const int m0 = sb * 16;
    const int m  = m0 + wv;

    __shared__ float sG[16][4][105];  // px-stride 420 floats -> bank offset 4/px
    __shared__ float sF[16][4][2];    // fx, fy

    // f1 fragment: 32 channels (64 B) per lane, reused across 4 levels x 100 pts
    const uint4* f1p = reinterpret_cast<const uint4*>(f1T + (size_t)m * CDIM + sub * 32);
    const uint4 F0 = f1p[0], F1 = f1p[1], F2 = f1p[2], F3 = f1p[3];

    const float cx = coords[m];
    const float cy = coords[HW + m];

    #pragma unroll
    for (int w = 0; w < 4; ++w) {
        const int Wl = W0 >> w;
        const int Hl = H0 >> w;
        const size_t lvl_off = (w == 0) ? 0u
                             : (w == 1) ? 2097152u
                             : (w == 2) ? 2621440u
                             :            2752512u;
        const _Float16* lvl = pyr + lvl_off;
        const float scale = 1.0f / (float)(1 << w);

        const float xs = cx * scale;
        const float ys = cy * scale;
        const float X0f = floorf(xs), Y0f = floorf(ys);
        const int X0 = (int)X0f, Y0 = (int)Y0f;
        if (lane == 0) { sF[wv][w][0] = xs - X0f; sF[wv][w][1] = ys - Y0f; }

        for (int it = 0; it < 13; ++it) {
            const int p = it * 8 + grp;           // grid point 0..103 (mask >=100)
            const int j = (p * 205) >> 11;        // p / 10
            const int i = p - j * 10;
            const int gy = Y0 - 4 + j;
            const int gx = X0 - 4 + i;
            float s = 0.0f;
            if (p < 100 && ((unsigned)gy < (unsigned)Hl) && ((unsigned)gx < (unsigned)Wl)) {
                const uint4* q = reinterpret_cast<const uint4*>(
                    lvl + ((size_t)(gy * Wl + gx) * CDIM) + sub * 32);
                const uint4 A = q[0], B = q[1], C = q[2], D = q[3];
                float s0 = 0.f, s1 = 0.f, s2 = 0.f, s3 = 0.f;
                s0 = dot2u(A.x, F0.x, s0); s0 = dot2u(A.y, F0.y, s0);
                s0 = dot2u(A.z, F0.z, s0); s0 = dot2u(A.w, F0.w, s0);
                s1 = dot2u(B.x, F1.x, s1); s1 = dot2u(B.y, F1.y, s1);
                s1 = dot2u(B.z, F1.z, s1); s1 = dot2u(B.w, F1.w, s1);
                s2 = dot2u(C.x, F2.x, s2); s2 = dot2u(C.y, F2.y, s2);
                s2 = dot2u(C.z, F2.z, s2); s2 = dot2u(C.w, F2.w, s2);
                s3 = dot2u(D.x, F3.x, s3); s3 = dot2u(D.y, F3.y, s3);
                s3 = dot2u(D.z, F3.z, s3); s3 = dot2u(D.w, F3.w, s3);
                s = (s0 + s1) + (s2 + s3);
            }
            // reduce across the 8 lanes of this point-group
            s += __shfl_xor(s, 1);
            s += __shfl_xor(s, 2);
            s += __shfl_xor(s, 4);
            if (sub == 0 && p < 100) sG[wv][w][p] = s;
        }
    }
    __syncthreads();

    // combine: thread t -> pixel (t&15), outputs (t>>4) + k*64
    const int cpx = tid & 15;
    for (int o = tid >> 4; o < 324; o += 64) {
        const int lev = (o * 811) >> 16;          // o / 81
        const int k   = o - lev * 81;
        const int a   = (k * 57) >> 9;            // k / 9  (x-offset index)
        const int bb  = k - a * 9;                // k % 9  (y-offset index)
        const float fx = sF[cpx][lev][0], fy = sF[cpx][lev][1];
        const float wx0 = 1.0f - fx, wy0 = 1.0f - fy;
        const float* G = sG[cpx][lev];
        const float v = wy0 * (wx0 * G[bb * 10 + a]       + fx * G[bb * 10 + a + 1])
                      + fy  * (wx0 * G[(bb + 1) * 10 + a] + fx * G[(bb + 1) * 10 + a + 1]);
        out[(size_t)o * HW + m0 + cpx] = v;
    }
}

extern "C" void kernel_launch(void* const* d_in, const int* in_sizes, int n_in,
                              void* d_out, int out_size, void* d_ws, size_t ws_size,
                              hipStream_t stream) {
    const float* fmap1  = (const float*)d_in[0];
    const float* fmap2  = (const float*)d_in[1];
    const float* coords = (const float*)d_in[2];
    float* out = (float*)d_out;

    char* ws = (char*)d_ws;
    _Float16* f1T = (_Float16*)ws;                          // 8192*256 f16 = 4 MiB
    _Float16* pyr = (_Float16*)(ws + 4194304);              // 2,785,280 f16 = 5.57 MB
    _Float16* p0 = pyr;                 // 64x128x256
    _Float16* p1 = pyr + 2097152;       // 32x64x256
    _Float16* p2 = pyr + 2621440;       // 16x32x256
    _Float16* p3 = pyr + 2752512;       //  8x16x256

    k_transpose_f1<<<HW / 32, 256, 0, stream>>>(fmap1, f1T);
    k_transpose_f2<<<HW / 32, 256, 0, stream>>>(fmap2, p0);
    k_pool<<<32 * 64, 256, 0, stream>>>(p0, p1, 64, 128);
    k_pool<<<16 * 32, 256, 0, stream>>>(p1, p2, 32, 64);
    k_pool<<<8 * 16, 256, 0, stream>>>(p2, p3, 16, 32);
    k_sample<<<HW / 16, 1024, 0, stream>>>(f1T, pyr, coords, out);
}